// Round 8
// baseline (264.616 us; speedup 1.0000x reference)
//
#include <hip/hip_runtime.h>
#include <hip/hip_bf16.h>

// Sizes fixed by the reference problem.
#define CN 32
#define RN 256
#define DN 512
#define NN 32
#define LN 256

// LDS layout of main kernel (bytes):
//  sAt   : bf16 [256][256] = 131072, 16B-chunk XOR swizzle (chunk ^= r&7).
//          During PHASE A the first 64KB of this region hosts 4 x 16KB
//          con staging buffers (sAt is only written after phase A).
//  stage : 32768 @131072 = double-buffered G staging, 16K per buffer.
//          Epilogue reductions (w12s 8K, nsqS 1K, red) overlay this region.
//  total : 163840 = 160 KiB.
// Shape is boxed (R15/R16): 512 threads / 8 waves / 2 per SIMD is the only
// config where acc (128 AGPR) + working set fit the 256-reg/wave budget.
#define STAGE_OFF 131072
#define SMEM_TOTAL 163840

typedef short v8s __attribute__((ext_vector_type(8)));
typedef float v4f __attribute__((ext_vector_type(4)));
typedef const __attribute__((address_space(1))) void* gas1_t;
typedef __attribute__((address_space(3))) void* las3_t;

__device__ __forceinline__ void gl2lds16(const void* g, void* l) {
  __builtin_amdgcn_global_load_lds((gas1_t)g, (las3_t)l, 16, 0, 0);
}

__device__ __forceinline__ unsigned short f2bf(float x) {
  unsigned int u = __float_as_uint(x);
  u = (u + 0x7fffu + ((u >> 16) & 1u)) >> 16;  // RNE
  return (unsigned short)u;
}
__device__ __forceinline__ float bf2f(unsigned short h) {
  return __uint_as_float(((unsigned int)h) << 16);
}

// Packed RNE f32x2 -> bf16x2 (v_cvt_pk_bf16_f32 on gfx950); a -> low 16.
__device__ __forceinline__ unsigned int pkbf(float a, float b) {
  __hip_bfloat162 h = __float22bfloat162_rn(make_float2(a, b));
  unsigned int u;
  __builtin_memcpy(&u, &h, sizeof(u));
  return u;
}

// Staging buffers ([256][32] shorts): 16B chunks XOR-swizzled with (r>>1)&3.
// Writes absorb the swizzle in the global fetch column; reads via this helper.
__device__ __forceinline__ const v8s* stgFrag(const unsigned short* buf, int r,
                                              int quad) {
  return (const v8s*)(buf + r * 32 + ((quad ^ ((r >> 1) & 3)) << 3));
}

// sAt addressing: row-major stride 256 shorts, 16B chunks XOR-swizzled by row.
__device__ __forceinline__ int satIdx(int r, int col) {
  return (r << 8) | ((((col >> 3) ^ (r & 7)) << 3) | (col & 7));
}

// Read an 8-float fragment from the fp32 gram slice [256][64] (32B chunks
// rotated by row) and convert to bf16x8.
__device__ __forceinline__ v8s ldFrag64(const float* buf, int r, int cp) {
  const float* p = buf + r * 64 + (((cp + r) & 7) << 3);
  const float4 x0 = ((const float4*)p)[0];
  const float4 x1 = ((const float4*)p)[1];
  unsigned short h[8];
  h[0] = f2bf(x0.x); h[1] = f2bf(x0.y); h[2] = f2bf(x0.z); h[3] = f2bf(x0.w);
  h[4] = f2bf(x1.x); h[5] = f2bf(x1.y); h[6] = f2bf(x1.z); h[7] = f2bf(x1.w);
  return *(v8s*)h;
}

// ---------------------------------------------------------------------------
// Fused setup: 256 blocks x 512 threads (1 block/CU). Each block: gram
// chunk-0 staging issued first, 1/256th of the bf16 conversions (hides the
// staging latency), then the double-buffered gram K-loop
// (G[n] = laws[n]@laws[n]^T, 32-row output stripe per block).
// ---------------------------------------------------------------------------
__global__ __launch_bounds__(512) void setup_kernel(
    const float* __restrict__ con, const float* __restrict__ laws,
    unsigned short* __restrict__ lawsB, unsigned short* __restrict__ conB,
    float* __restrict__ cnorm, unsigned short* __restrict__ G) {
  extern __shared__ float slice[];  // 2 x [256*64] fp32, row-rotated 32B chunks
  const int bid = blockIdx.x;       // 256 blocks
  const int t = threadIdx.x;
  const int n = bid >> 3;
  const int m0 = (bid & 7) << 5;  // 32-row output stripe of G[n]
  const int lane = t & 63;
  const int w = t >> 6;
  const int quad = lane >> 4;
  const int l16 = lane & 15;
  const int rg = w >> 2;  // 0..1
  const int cg = w & 3;   // 0..3
  const float* lawN = laws + n * (LN * DN);

  // (1) Issue gram chunk-0 staging into buf0 (in flight during conversions).
#pragma unroll
  for (int i = 0; i < 8; ++i) {
    const int s = i * 512 + t;
    const int row = s >> 4;
    const int p = s & 15;
    const int srcCol = ((((p >> 1) - row) & 7) << 3) + ((p & 1) << 2);
    gl2lds16(lawN + row * DN + srcCol, (char*)slice + s * 16);
  }

  // (2a) laws fp32 -> bf16: this block's 16384-float slice.
#pragma unroll
  for (int p = 0; p < 4; ++p) {
    const int off = bid * 16384 + p * 4096 + t * 8;
    const float4* src = (const float4*)(laws + off);
    float4 x0 = src[0], x1 = src[1];
    unsigned short h[8];
    h[0] = f2bf(x0.x); h[1] = f2bf(x0.y); h[2] = f2bf(x0.z); h[3] = f2bf(x0.w);
    h[4] = f2bf(x1.x); h[5] = f2bf(x1.y); h[6] = f2bf(x1.z); h[7] = f2bf(x1.w);
    *(v8s*)(lawsB + off) = *(v8s*)h;
  }
  // (2b) contracts fp32 -> bf16 + row norms: 32 rows (one wave-row per pass).
#pragma unroll
  for (int p = 0; p < 4; ++p) {
    const int r = bid * 32 + p * 8 + w;
    const float4* src = (const float4*)(con + r * DN + lane * 8);
    float4 x0 = src[0], x1 = src[1];
    unsigned short h[8];
    h[0] = f2bf(x0.x); h[1] = f2bf(x0.y); h[2] = f2bf(x0.z); h[3] = f2bf(x0.w);
    h[4] = f2bf(x1.x); h[5] = f2bf(x1.y); h[6] = f2bf(x1.z); h[7] = f2bf(x1.w);
    *(v8s*)(conB + r * DN + lane * 8) = *(v8s*)h;
    float s = x0.x * x0.x + x0.y * x0.y + x0.z * x0.z + x0.w * x0.w +
              x1.x * x1.x + x1.y * x1.y + x1.z * x1.z + x1.w * x1.w;
#pragma unroll
    for (int m = 1; m < 64; m <<= 1) s += __shfl_xor(s, m, 64);
    if (lane == 0) cnorm[r] = sqrtf(s);
  }

  // (3) Gram K-loop, double-buffered.
  v4f acc[4];
#pragma unroll
  for (int b = 0; b < 4; ++b) acc[b] = (v4f){0.f, 0.f, 0.f, 0.f};

  for (int ch = 0; ch < 8; ++ch) {
    __syncthreads();  // buf[ch&1] staged (chunk-ch load has been in flight)
    if (ch < 7) {     // prefetch chunk ch+1 into the other buffer
      const int dk = (ch + 1) << 6;
      char* dst = (char*)slice + ((ch + 1) & 1) * 65536;
#pragma unroll
      for (int i = 0; i < 8; ++i) {
        const int s = i * 512 + t;
        const int row = s >> 4;
        const int p = s & 15;
        const int srcCol = ((((p >> 1) - row) & 7) << 3) + ((p & 1) << 2);
        gl2lds16(lawN + row * DN + dk + srcCol, dst + s * 16);
      }
    }
    const float* buf = slice + (ch & 1) * 16384;
#pragma unroll
    for (int step = 0; step < 2; ++step) {
      const int cp = quad + (step << 2);
      v8s af = ldFrag64(buf, m0 + rg * 16 + l16, cp);
#pragma unroll
      for (int ct = 0; ct < 4; ++ct) {
        v8s bf = ldFrag64(buf, cg * 64 + ct * 16 + l16, cp);
        acc[ct] = __builtin_amdgcn_mfma_f32_16x16x32_bf16(af, bf, acc[ct], 0, 0, 0);
      }
    }
  }
  unsigned short* g = G + n * (LN * LN);
#pragma unroll
  for (int ct = 0; ct < 4; ++ct)
#pragma unroll
    for (int reg = 0; reg < 4; ++reg) {
      const int l = m0 + rg * 16 + quad * 4 + reg;
      g[l * LN + cg * 64 + ct * 16 + l16] = f2bf(acc[ct][reg]);
    }
}

// ---------------------------------------------------------------------------
// Main: one block per (n,c), 512 threads (8 waves). R17/R18 structure + R19:
// (1) Phase A uses COUNTED-vmcnt pipelining (T3/T4): 4 x 16KB staging
//     buffers in the (phase-A-dead) sAt region, staged 3 chunks ahead; raw
//     s_barrier + exact s_waitcnt vmcnt(N) replaces __syncthreads, so
//     prefetches stay in flight ACROSS barriers (never drained to 0).
//     FIFO accounting (per thread, 2 gl2lds + 2 af loads per iter):
//     newer-than-st(ch) = 8 steady; edges 6 (ch=0), 6 (ch=14), 4 (ch=15).
//     W-A-R safe: every staged byte feeds an MFMA whose issue forces its
//     ds_read to complete, so all LDS reads are done at barrier arrival.
// (2) nsq tile guard: wave-uniform `if (lt*16 < len)` skips exact-zero
//     tiles (static lt / static acc indices -- not the R14 MFMA-loop case).
// ---------------------------------------------------------------------------
__global__ __launch_bounds__(512, 2) void main_kernel(
    const int* __restrict__ law_lens, const unsigned short* __restrict__ lawsB,
    const unsigned short* __restrict__ conB, const unsigned short* __restrict__ Gm,
    const float* __restrict__ cnorm, float* __restrict__ out) {
  extern __shared__ char smem[];
  unsigned short* sAt = (unsigned short*)smem;  // [256][256] swizzled
  char* abuf = smem;                            // phase-A: 4 x 16K staging
  char* stage = smem + STAGE_OFF;               // 2 x 16K (G staging, phase C)

  const int bid = blockIdx.x;
  const int n = bid >> 5;  // 32 consecutive blocks share one n
  const int c = bid & 31;
  const int t = threadIdx.x;
  const int lane = t & 63;
  const int w = t >> 6;  // wave 0..7
  const int quad = lane >> 4;
  const int l16 = lane & 15;
  const int sub = t & 3;
  const int rQ = t >> 2;                   // 0..127
  const int subx = sub ^ ((rQ >> 1) & 3);  // swizzled source chunk
  const int len = law_lens[n];
  const int nCh = (len + 31) >> 5;         // phase-B k-chunks (block-uniform)
  const bool active = (w * 32) < len;      // wave has live l-rows in phase A

  const unsigned short* lawN = lawsB + n * (LN * DN);
  const unsigned short* conC = conB + c * (RN * DN);
  const unsigned short* Gn = Gm + n * (LN * LN);

  float w12p[16];
#pragma unroll
  for (int i = 0; i < 16; ++i) w12p[i] = 0.f;

  // ---------------- Phase A ----------------
  {
    const unsigned short* a0p = lawN + (w * 32 + l16) * DN + quad * 8;
    const unsigned short* a1p = a0p + 16 * DN;

    v4f acc[2][16];
#pragma unroll
    for (int a = 0; a < 2; ++a)
#pragma unroll
      for (int b = 0; b < 16; ++b) acc[a][b] = (v4f){0.f, 0.f, 0.f, 0.f};

    // Prologue, emission order PINNED (st0, st1, af0, st2) so the per-iter
    // vmcnt counts below are exact.
#pragma unroll
    for (int i = 0; i < 2; ++i)
      gl2lds16(conC + (i * 128 + rQ) * DN + 0 + subx * 8,
               abuf + 0 * 16384 + i * 8192 + t * 16);
    __builtin_amdgcn_sched_barrier(0);
#pragma unroll
    for (int i = 0; i < 2; ++i)
      gl2lds16(conC + (i * 128 + rQ) * DN + 32 + subx * 8,
               abuf + 1 * 16384 + i * 8192 + t * 16);
    __builtin_amdgcn_sched_barrier(0);
    v8s afC0 = *(const v8s*)(a0p);
    v8s afC1 = *(const v8s*)(a1p);
    __builtin_amdgcn_sched_barrier(0);
#pragma unroll
    for (int i = 0; i < 2; ++i)
      gl2lds16(conC + (i * 128 + rQ) * DN + 64 + subx * 8,
               abuf + 2 * 16384 + i * 8192 + t * 16);
    __builtin_amdgcn_sched_barrier(0);

#pragma unroll
    for (int ch = 0; ch < 16; ++ch) {
      // Exact counted wait: drain st(ch) (and everything older), keep the
      // newer prefetches + af loads in flight across the barrier.
      if (ch == 0)
        asm volatile("s_waitcnt vmcnt(6)" ::: "memory");
      else if (ch <= 13)
        asm volatile("s_waitcnt vmcnt(8)" ::: "memory");
      else if (ch == 14)
        asm volatile("s_waitcnt vmcnt(6)" ::: "memory");
      else
        asm volatile("s_waitcnt vmcnt(4)" ::: "memory");
      __builtin_amdgcn_s_barrier();
      __builtin_amdgcn_sched_barrier(0);
      v8s afN0, afN1;
      if (ch < 15) {  // af(ch+1) register prefetch
        const int dkn = (ch + 1) << 5;
        afN0 = *(const v8s*)(a0p + dkn);
        afN1 = *(const v8s*)(a1p + dkn);
      }
      if (ch + 3 < 16) {  // st(ch+3): stage 3 chunks ahead
        const int dkn = (ch + 3) << 5;
        char* dst = abuf + ((ch + 3) & 3) * 16384;
#pragma unroll
        for (int i = 0; i < 2; ++i)
          gl2lds16(conC + (i * 128 + rQ) * DN + dkn + subx * 8,
                   dst + i * 8192 + t * 16);
      }
      __builtin_amdgcn_sched_barrier(0);
      if (active) {  // wave-uniform: inactive waves produce only zeros below
        const unsigned short* cs =
            (const unsigned short*)(abuf + (ch & 3) * 16384);
        __builtin_amdgcn_s_setprio(1);
#pragma unroll
        for (int rt = 0; rt < 16; ++rt) {
          v8s bf = *stgFrag(cs, rt * 16 + l16, quad);
          acc[0][rt] = __builtin_amdgcn_mfma_f32_16x16x32_bf16(afC0, bf, acc[0][rt], 0, 0, 0);
          acc[1][rt] = __builtin_amdgcn_mfma_f32_16x16x32_bf16(afC1, bf, acc[1][rt], 0, 0, 0);
        }
        __builtin_amdgcn_s_setprio(0);
      }
      if (ch < 15) {
        afC0 = afN0;
        afC1 = afN1;
      }
    }

    __syncthreads();  // full drain; abuf region becomes sAt-writable

    // Hoisted: stage G chunks 0 AND 1 NOW (stage buf0/buf1) -- latency hides
    // under the softmax VALU below; phase B's first barrier drains both.
#pragma unroll
    for (int i = 0; i < 2; ++i)
      gl2lds16(Gn + (i * 128 + rQ) * LN + subx * 8, stage + i * 8192 + t * 16);
#pragma unroll
    for (int i = 0; i < 2; ++i)
      gl2lds16(Gn + (i * 128 + rQ) * LN + 32 + subx * 8,
               stage + 16384 + i * 8192 + t * 16);

    if (active) {
      // Softmax row ops (streaming; |lv*inv| <= 1 so exp needs no max-sub).
      // Row l lives in 16 lanes (C layout col=lane&15 -> r index). 4 regs =
      // 4 consecutive sAt columns -> packed cvt + b64 writes.
#pragma unroll
      for (int tl = 0; tl < 2; ++tl) {
        unsigned int pk[16][2];
        float a0s[16];
#pragma unroll
        for (int reg = 0; reg < 4; ++reg) {
          const int lg = w * 32 + tl * 16 + quad * 4 + reg;
          float ss = 0.f;
#pragma unroll
          for (int rt = 0; rt < 16; ++rt) {
            const float v = acc[tl][rt][reg] * 0.04419417382415922f;
            const float lv = v > 0.f ? v : 0.1f * v;
            ss += lv * lv;
          }
#pragma unroll
          for (int m = 1; m < 16; m <<= 1) ss += __shfl_xor(ss, m, 64);
          const float inv = 1.f / (sqrtf(ss) + 1e-8f);
          float e[16];
          float den = 0.f;
#pragma unroll
          for (int rt = 0; rt < 16; ++rt) {
            const float v = acc[tl][rt][reg] * 0.04419417382415922f;
            const float lv = v > 0.f ? v : 0.1f * v;
            e[rt] = __expf(lv * inv);
            den += e[rt];
          }
#pragma unroll
          for (int m = 1; m < 16; m <<= 1) den += __shfl_xor(den, m, 64);
          const float sc = (lg < len) ? 4.f / den : 0.f;  // SMOOTH, masked
#pragma unroll
          for (int rt = 0; rt < 16; ++rt) {
            const float v = acc[tl][rt][reg] * 0.04419417382415922f;
            const float a = e[rt] * sc;
            w12p[rt] += a * v;  // raw S -> cosine numerator
            if (reg & 1)
              pk[rt][reg >> 1] = pkbf(a0s[rt], a);
            else
              a0s[rt] = a;
          }
        }
        const int lg0 = w * 32 + tl * 16 + quad * 4;
#pragma unroll
        for (int rt = 0; rt < 16; ++rt)
          *(uint2*)(sAt + satIdx(rt * 16 + l16, lg0)) = *(uint2*)pk[rt];
      }
    } else {
      // Zero this wave's sAt columns so nsq's full-width reads see exact
      // zeros (attn == 0 beyond len).
      uint2 z;
      z.x = 0u;
      z.y = 0u;
#pragma unroll
      for (int tl = 0; tl < 2; ++tl) {
        const int lg0 = w * 32 + tl * 16 + quad * 4;
#pragma unroll
        for (int rt = 0; rt < 16; ++rt)
          *(uint2*)(sAt + satIdx(rt * 16 + l16, lg0)) = z;
      }
    }
  }

  // Reduce w12 partials across quads; keep in registers through phase B.
  // (Inactive waves contribute zeros.)
#pragma unroll
  for (int rt = 0; rt < 16; ++rt) {
    w12p[rt] += __shfl_xor(w12p[rt], 16, 64);
    w12p[rt] += __shfl_xor(w12p[rt], 32, 64);
  }

  // ---------------- Phase B (k capped at nCh = ceil(len/32)) ----------------
  float nsv[2][4];
  {
    v4f acc[2][16];
#pragma unroll
    for (int a = 0; a < 2; ++a)
#pragma unroll
      for (int b = 0; b < 16; ++b) acc[a][b] = (v4f){0.f, 0.f, 0.f, 0.f};

    __syncthreads();  // sAt writes complete; G chunks 0,1 staged (drained)

    for (int ch = 0; ch < nCh; ++ch) {
      const int lk = ch << 5;
      if (ch) __syncthreads();  // drains chunk-ch staging; frees buf[(ch+1)&1]
      v8s af0 = *(const v8s*)(sAt + satIdx(w * 32 + l16, lk + quad * 8));
      v8s af1 = *(const v8s*)(sAt + satIdx(w * 32 + 16 + l16, lk + quad * 8));
      __builtin_amdgcn_sched_barrier(0);
      if (ch > 0 && ch < nCh - 1) {  // prefetch chunk ch+1 (ch0/ch1 hoisted)
        char* dst = stage + ((ch + 1) & 1) * 16384;
#pragma unroll
        for (int i = 0; i < 2; ++i)
          gl2lds16(Gn + (i * 128 + rQ) * LN + (lk + 32) + subx * 8,
                   dst + i * 8192 + t * 16);
      }
      __builtin_amdgcn_sched_barrier(0);
      const unsigned short* gs =
          (const unsigned short*)(stage + (ch & 1) * 16384);
      __builtin_amdgcn_s_setprio(1);
#pragma unroll
      for (int lt = 0; lt < 16; ++lt) {
        v8s bf = *stgFrag(gs, lt * 16 + l16, quad);  // G row (symmetric)
        acc[0][lt] = __builtin_amdgcn_mfma_f32_16x16x32_bf16(af0, bf, acc[0][lt], 0, 0, 0);
        acc[1][lt] = __builtin_amdgcn_mfma_f32_16x16x32_bf16(af1, bf, acc[1][lt], 0, 0, 0);
      }
      __builtin_amdgcn_s_setprio(0);
    }
    // nsq[r] = sum_l At[r,l] * U[r,l]; tiles with lt*16 >= len are exact
    // zeros in sAt -> skip (wave-uniform branch, static lt/acc indexing).
#pragma unroll
    for (int tl = 0; tl < 2; ++tl) {
#pragma unroll
      for (int reg = 0; reg < 4; ++reg) {
        const int r = w * 32 + tl * 16 + quad * 4 + reg;
        float s = 0.f;
#pragma unroll
        for (int lt = 0; lt < 16; ++lt) {
          if ((lt << 4) < len)
            s += acc[tl][lt][reg] * bf2f(sAt[satIdx(r, lt * 16 + l16)]);
        }
#pragma unroll
        for (int m = 1; m < 16; m <<= 1) s += __shfl_xor(s, m, 64);
        nsv[tl][reg] = s;
      }
    }
  }

  // ---------------- Phase C (reductions overlay the stage region) ----------
  float* w12s = (float*)stage;           // [8][256] = 8K
  float* nsqS = (float*)(stage + 8192);  // [256]    = 1K
  float* red = (float*)(stage + 9216);   // [8]
  __syncthreads();  // all Gs reads done; stage is free for reductions
  if (l16 == 0) {
#pragma unroll
    for (int tl = 0; tl < 2; ++tl)
#pragma unroll
      for (int reg = 0; reg < 4; ++reg)
        nsqS[w * 32 + tl * 16 + quad * 4 + reg] = nsv[tl][reg];
  }
  if (lane < 16) {
#pragma unroll
    for (int rt = 0; rt < 16; ++rt) w12s[w * 256 + rt * 16 + lane] = w12p[rt];
  }
  __syncthreads();
  float p = 0.f;
  if (t < 256) {
    float w12 = 0.f;
#pragma unroll
    for (int i = 0; i < 8; ++i) w12 += w12s[i * 256 + t];
    const float w1 = cnorm[c * RN + t];
    const float w2 = sqrtf(fmaxf(nsqS[t], 0.f));
    const float sim = (w12 * 22.627416997969522f) / fmaxf(w1 * w2, 1e-8f);
    p = __expf(6.f * sim);
  }
#pragma unroll
  for (int m = 1; m < 64; m <<= 1) p += __shfl_xor(p, m, 64);
  if (lane == 0) red[w] = p;
  __syncthreads();
  if (t == 0) {
    float s = 0.f;
#pragma unroll
    for (int i = 0; i < 8; ++i) s += red[i];
    out[c * NN + n] = logf(s) / 6.f;
  }
}

// ---------------------------------------------------------------------------
extern "C" void kernel_launch(void* const* d_in, const int* in_sizes, int n_in,
                              void* d_out, int out_size, void* d_ws, size_t ws_size,
                              hipStream_t stream) {
  (void)in_sizes; (void)n_in; (void)out_size;
  const float* contracts = (const float*)d_in[0];
  const float* laws = (const float*)d_in[1];
  const int* law_lens = (const int*)d_in[2];
  float* out = (float*)d_out;

  // Workspace layout (21,004,288 B total)
  unsigned short* lawsB = (unsigned short*)d_ws;  // 8 MiB
  unsigned short* conB = lawsB + NN * LN * DN;    // 8 MiB
  unsigned short* G = conB + CN * RN * DN;        // 4 MiB
  float* cnorm = (float*)(G + NN * LN * LN);      // 32 KiB
  if (ws_size < (size_t)21004288) return;

  hipFuncSetAttribute((const void*)setup_kernel,
                      hipFuncAttributeMaxDynamicSharedMemorySize, 131072);
  hipFuncSetAttribute((const void*)main_kernel,
                      hipFuncAttributeMaxDynamicSharedMemorySize, SMEM_TOTAL);

  // 256 blocks: gram stripe + 1/256th of the bf16 conversions each.
  setup_kernel<<<256, 512, 131072, stream>>>(contracts, laws, lawsB, conB,
                                             cnorm, G);
  main_kernel<<<1024, 512, SMEM_TOTAL, stream>>>(law_lens, lawsB, conB, G,
                                                 cnorm, out);
}

// Round 9
// 240.132 us; speedup vs baseline: 1.1020x; 1.1020x over previous
//
#include <hip/hip_runtime.h>
#include <hip/hip_bf16.h>

// Sizes fixed by the reference problem.
#define CN 32
#define RN 256
#define DN 512
#define NN 32
#define LN 256

// LDS layout of main kernel (bytes):
//  sAt   : bf16 [256][256] = 131072, 16B-chunk XOR swizzle (chunk ^= r&7)
//  stage : 32768 = double-buffered staging (conS / Gs), 16K per buffer.
//          Epilogue reductions (w12s 8K, nsqS 1K, red) overlay this region.
//  total : 163840 = 160 KiB.
// Design-space map (measured): 512 threads / 8 waves / 2 per SIMD is the
// ONLY shape where acc (128 AGPR) + working set fit the 256-reg/wave budget
// (R15: M=64 spills; R16: 16-wave 128-reg cap spills). Counted-vmcnt phase-A
// pipelining (R19) also spills: af regs must live across barriers (+16 VGPR
// + pinned ranges -> 39.5MB scratch). R18's __syncthreads + af reg dbuf +
// setprio is the measured optimum of this structure (147.2us main).
#define STAGE_OFF 131072
#define SMEM_TOTAL 163840

typedef short v8s __attribute__((ext_vector_type(8)));
typedef float v4f __attribute__((ext_vector_type(4)));
typedef const __attribute__((address_space(1))) void* gas1_t;
typedef __attribute__((address_space(3))) void* las3_t;

__device__ __forceinline__ void gl2lds16(const void* g, void* l) {
  __builtin_amdgcn_global_load_lds((gas1_t)g, (las3_t)l, 16, 0, 0);
}

__device__ __forceinline__ unsigned short f2bf(float x) {
  unsigned int u = __float_as_uint(x);
  u = (u + 0x7fffu + ((u >> 16) & 1u)) >> 16;  // RNE
  return (unsigned short)u;
}
__device__ __forceinline__ float bf2f(unsigned short h) {
  return __uint_as_float(((unsigned int)h) << 16);
}

// Packed RNE f32x2 -> bf16x2 (v_cvt_pk_bf16_f32 on gfx950); a -> low 16.
__device__ __forceinline__ unsigned int pkbf(float a, float b) {
  __hip_bfloat162 h = __float22bfloat162_rn(make_float2(a, b));
  unsigned int u;
  __builtin_memcpy(&u, &h, sizeof(u));
  return u;
}

// Staging buffers ([256][32] shorts): 16B chunks XOR-swizzled with (r>>1)&3.
// Writes absorb the swizzle in the global fetch column; reads via this helper.
__device__ __forceinline__ const v8s* stgFrag(const unsigned short* buf, int r,
                                              int quad) {
  return (const v8s*)(buf + r * 32 + ((quad ^ ((r >> 1) & 3)) << 3));
}

// sAt addressing: row-major stride 256 shorts, 16B chunks XOR-swizzled by row.
__device__ __forceinline__ int satIdx(int r, int col) {
  return (r << 8) | ((((col >> 3) ^ (r & 7)) << 3) | (col & 7));
}

// Read an 8-float fragment from the fp32 gram slice [256][64] (32B chunks
// rotated by row) and convert to bf16x8.
__device__ __forceinline__ v8s ldFrag64(const float* buf, int r, int cp) {
  const float* p = buf + r * 64 + (((cp + r) & 7) << 3);
  const float4 x0 = ((const float4*)p)[0];
  const float4 x1 = ((const float4*)p)[1];
  unsigned short h[8];
  h[0] = f2bf(x0.x); h[1] = f2bf(x0.y); h[2] = f2bf(x0.z); h[3] = f2bf(x0.w);
  h[4] = f2bf(x1.x); h[5] = f2bf(x1.y); h[6] = f2bf(x1.z); h[7] = f2bf(x1.w);
  return *(v8s*)h;
}

// ---------------------------------------------------------------------------
// Fused setup: 256 blocks x 512 threads (1 block/CU). Each block: gram
// chunk-0 staging issued first, 1/256th of the bf16 conversions (hides the
// staging latency), then the double-buffered gram K-loop
// (G[n] = laws[n]@laws[n]^T, 32-row output stripe per block).
// ---------------------------------------------------------------------------
__global__ __launch_bounds__(512) void setup_kernel(
    const float* __restrict__ con, const float* __restrict__ laws,
    unsigned short* __restrict__ lawsB, unsigned short* __restrict__ conB,
    float* __restrict__ cnorm, unsigned short* __restrict__ G) {
  extern __shared__ float slice[];  // 2 x [256*64] fp32, row-rotated 32B chunks
  const int bid = blockIdx.x;       // 256 blocks
  const int t = threadIdx.x;
  const int n = bid >> 3;
  const int m0 = (bid & 7) << 5;  // 32-row output stripe of G[n]
  const int lane = t & 63;
  const int w = t >> 6;
  const int quad = lane >> 4;
  const int l16 = lane & 15;
  const int rg = w >> 2;  // 0..1
  const int cg = w & 3;   // 0..3
  const float* lawN = laws + n * (LN * DN);

  // (1) Issue gram chunk-0 staging into buf0 (in flight during conversions).
#pragma unroll
  for (int i = 0; i < 8; ++i) {
    const int s = i * 512 + t;
    const int row = s >> 4;
    const int p = s & 15;
    const int srcCol = ((((p >> 1) - row) & 7) << 3) + ((p & 1) << 2);
    gl2lds16(lawN + row * DN + srcCol, (char*)slice + s * 16);
  }

  // (2a) laws fp32 -> bf16: this block's 16384-float slice.
#pragma unroll
  for (int p = 0; p < 4; ++p) {
    const int off = bid * 16384 + p * 4096 + t * 8;
    const float4* src = (const float4*)(laws + off);
    float4 x0 = src[0], x1 = src[1];
    unsigned short h[8];
    h[0] = f2bf(x0.x); h[1] = f2bf(x0.y); h[2] = f2bf(x0.z); h[3] = f2bf(x0.w);
    h[4] = f2bf(x1.x); h[5] = f2bf(x1.y); h[6] = f2bf(x1.z); h[7] = f2bf(x1.w);
    *(v8s*)(lawsB + off) = *(v8s*)h;
  }
  // (2b) contracts fp32 -> bf16 + row norms: 32 rows (one wave-row per pass).
#pragma unroll
  for (int p = 0; p < 4; ++p) {
    const int r = bid * 32 + p * 8 + w;
    const float4* src = (const float4*)(con + r * DN + lane * 8);
    float4 x0 = src[0], x1 = src[1];
    unsigned short h[8];
    h[0] = f2bf(x0.x); h[1] = f2bf(x0.y); h[2] = f2bf(x0.z); h[3] = f2bf(x0.w);
    h[4] = f2bf(x1.x); h[5] = f2bf(x1.y); h[6] = f2bf(x1.z); h[7] = f2bf(x1.w);
    *(v8s*)(conB + r * DN + lane * 8) = *(v8s*)h;
    float s = x0.x * x0.x + x0.y * x0.y + x0.z * x0.z + x0.w * x0.w +
              x1.x * x1.x + x1.y * x1.y + x1.z * x1.z + x1.w * x1.w;
#pragma unroll
    for (int m = 1; m < 64; m <<= 1) s += __shfl_xor(s, m, 64);
    if (lane == 0) cnorm[r] = sqrtf(s);
  }

  // (3) Gram K-loop, double-buffered.
  v4f acc[4];
#pragma unroll
  for (int b = 0; b < 4; ++b) acc[b] = (v4f){0.f, 0.f, 0.f, 0.f};

  for (int ch = 0; ch < 8; ++ch) {
    __syncthreads();  // buf[ch&1] staged (chunk-ch load has been in flight)
    if (ch < 7) {     // prefetch chunk ch+1 into the other buffer
      const int dk = (ch + 1) << 6;
      char* dst = (char*)slice + ((ch + 1) & 1) * 65536;
#pragma unroll
      for (int i = 0; i < 8; ++i) {
        const int s = i * 512 + t;
        const int row = s >> 4;
        const int p = s & 15;
        const int srcCol = ((((p >> 1) - row) & 7) << 3) + ((p & 1) << 2);
        gl2lds16(lawN + row * DN + dk + srcCol, dst + s * 16);
      }
    }
    const float* buf = slice + (ch & 1) * 16384;
#pragma unroll
    for (int step = 0; step < 2; ++step) {
      const int cp = quad + (step << 2);
      v8s af = ldFrag64(buf, m0 + rg * 16 + l16, cp);
#pragma unroll
      for (int ct = 0; ct < 4; ++ct) {
        v8s bf = ldFrag64(buf, cg * 64 + ct * 16 + l16, cp);
        acc[ct] = __builtin_amdgcn_mfma_f32_16x16x32_bf16(af, bf, acc[ct], 0, 0, 0);
      }
    }
  }
  unsigned short* g = G + n * (LN * LN);
#pragma unroll
  for (int ct = 0; ct < 4; ++ct)
#pragma unroll
    for (int reg = 0; reg < 4; ++reg) {
      const int l = m0 + rg * 16 + quad * 4 + reg;
      g[l * LN + cg * 64 + ct * 16 + l16] = f2bf(acc[ct][reg]);
    }
}

// ---------------------------------------------------------------------------
// Main: one block per (n,c), 512 threads (8 waves). R18 structure (best
// measured: 147.2us main) + R20: nsq tile guard -- tiles with lt*16 >= len
// are exact zeros in sAt, so the scalar read+FMA is skipped (wave-uniform
// branch, static lt / static acc indexing; NOT the R14 MFMA-loop case).
// ---------------------------------------------------------------------------
__global__ __launch_bounds__(512, 2) void main_kernel(
    const int* __restrict__ law_lens, const unsigned short* __restrict__ lawsB,
    const unsigned short* __restrict__ conB, const unsigned short* __restrict__ Gm,
    const float* __restrict__ cnorm, float* __restrict__ out) {
  extern __shared__ char smem[];
  unsigned short* sAt = (unsigned short*)smem;  // [256][256] swizzled
  char* stage = smem + STAGE_OFF;               // 2 x 16K buffers

  const int bid = blockIdx.x;
  const int n = bid >> 5;  // 32 consecutive blocks share one n
  const int c = bid & 31;
  const int t = threadIdx.x;
  const int lane = t & 63;
  const int w = t >> 6;  // wave 0..7
  const int quad = lane >> 4;
  const int l16 = lane & 15;
  const int sub = t & 3;
  const int rQ = t >> 2;                   // 0..127
  const int subx = sub ^ ((rQ >> 1) & 3);  // swizzled source chunk
  const int len = law_lens[n];
  const int nCh = (len + 31) >> 5;         // phase-B k-chunks (block-uniform)
  const bool active = (w * 32) < len;      // wave has live l-rows in phase A

  const unsigned short* lawN = lawsB + n * (LN * DN);
  const unsigned short* conC = conB + c * (RN * DN);
  const unsigned short* Gn = Gm + n * (LN * LN);

  float w12p[16];
#pragma unroll
  for (int i = 0; i < 16; ++i) w12p[i] = 0.f;

  // ---------------- Phase A ----------------
  {
    const unsigned short* a0p = lawN + (w * 32 + l16) * DN + quad * 8;
    const unsigned short* a1p = a0p + 16 * DN;

    v4f acc[2][16];
#pragma unroll
    for (int a = 0; a < 2; ++a)
#pragma unroll
      for (int b = 0; b < 16; ++b) acc[a][b] = (v4f){0.f, 0.f, 0.f, 0.f};

    // Prologue: stage con chunk 0 into buf0 + load af(chunk 0) into afA.
#pragma unroll
    for (int i = 0; i < 2; ++i)
      gl2lds16(conC + (i * 128 + rQ) * DN + subx * 8,
               stage + i * 8192 + t * 16);
    v8s afA0 = *(const v8s*)(a0p);
    v8s afA1 = *(const v8s*)(a1p);

#pragma unroll
    for (int ch = 0; ch < 16; ch += 2) {
      // ---- even chunk ch: compute from buf0 with afA; prefetch ch+1 ----
      __syncthreads();  // drains chunk-ch staging + afA loads (all overlapped)
      v8s afB0, afB1;
      {
        const int dkn = (ch + 1) << 5;  // ch+1 <= 15 always here
#pragma unroll
        for (int i = 0; i < 2; ++i)
          gl2lds16(conC + (i * 128 + rQ) * DN + dkn + subx * 8,
                   stage + 16384 + i * 8192 + t * 16);
        afB0 = *(const v8s*)(a0p + dkn);
        afB1 = *(const v8s*)(a1p + dkn);
      }
      __builtin_amdgcn_sched_barrier(0);
      if (active) {  // wave-uniform: inactive waves produce only zeros below
        const unsigned short* cs = (const unsigned short*)stage;
        __builtin_amdgcn_s_setprio(1);
#pragma unroll
        for (int rt = 0; rt < 16; ++rt) {
          v8s bf = *stgFrag(cs, rt * 16 + l16, quad);
          acc[0][rt] = __builtin_amdgcn_mfma_f32_16x16x32_bf16(afA0, bf, acc[0][rt], 0, 0, 0);
          acc[1][rt] = __builtin_amdgcn_mfma_f32_16x16x32_bf16(afA1, bf, acc[1][rt], 0, 0, 0);
        }
        __builtin_amdgcn_s_setprio(0);
      }
      // ---- odd chunk ch+1: compute from buf1 with afB; prefetch ch+2 ----
      __syncthreads();  // drains chunk-(ch+1) staging + afB loads
      if (ch + 2 < 16) {
        const int dkn = (ch + 2) << 5;
#pragma unroll
        for (int i = 0; i < 2; ++i)
          gl2lds16(conC + (i * 128 + rQ) * DN + dkn + subx * 8,
                   stage + i * 8192 + t * 16);
        afA0 = *(const v8s*)(a0p + dkn);
        afA1 = *(const v8s*)(a1p + dkn);
      }
      __builtin_amdgcn_sched_barrier(0);
      if (active) {
        const unsigned short* cs = (const unsigned short*)(stage + 16384);
        __builtin_amdgcn_s_setprio(1);
#pragma unroll
        for (int rt = 0; rt < 16; ++rt) {
          v8s bf = *stgFrag(cs, rt * 16 + l16, quad);
          acc[0][rt] = __builtin_amdgcn_mfma_f32_16x16x32_bf16(afB0, bf, acc[0][rt], 0, 0, 0);
          acc[1][rt] = __builtin_amdgcn_mfma_f32_16x16x32_bf16(afB1, bf, acc[1][rt], 0, 0, 0);
        }
        __builtin_amdgcn_s_setprio(0);
      }
    }

    __syncthreads();  // all staging reads done; both stage buffers reusable

    // Hoisted: stage G chunks 0 AND 1 NOW (buf0 and buf1) -- latency hides
    // under the softmax VALU below; phase B's first barrier drains both.
#pragma unroll
    for (int i = 0; i < 2; ++i)
      gl2lds16(Gn + (i * 128 + rQ) * LN + subx * 8, stage + i * 8192 + t * 16);
#pragma unroll
    for (int i = 0; i < 2; ++i)
      gl2lds16(Gn + (i * 128 + rQ) * LN + 32 + subx * 8,
               stage + 16384 + i * 8192 + t * 16);

    if (active) {
      // Softmax row ops (streaming; |lv*inv| <= 1 so exp needs no max-sub).
      // Row l lives in 16 lanes (C layout col=lane&15 -> r index). 4 regs =
      // 4 consecutive sAt columns -> packed cvt + b64 writes.
#pragma unroll
      for (int tl = 0; tl < 2; ++tl) {
        unsigned int pk[16][2];
        float a0s[16];
#pragma unroll
        for (int reg = 0; reg < 4; ++reg) {
          const int lg = w * 32 + tl * 16 + quad * 4 + reg;
          float ss = 0.f;
#pragma unroll
          for (int rt = 0; rt < 16; ++rt) {
            const float v = acc[tl][rt][reg] * 0.04419417382415922f;
            const float lv = v > 0.f ? v : 0.1f * v;
            ss += lv * lv;
          }
#pragma unroll
          for (int m = 1; m < 16; m <<= 1) ss += __shfl_xor(ss, m, 64);
          const float inv = 1.f / (sqrtf(ss) + 1e-8f);
          float e[16];
          float den = 0.f;
#pragma unroll
          for (int rt = 0; rt < 16; ++rt) {
            const float v = acc[tl][rt][reg] * 0.04419417382415922f;
            const float lv = v > 0.f ? v : 0.1f * v;
            e[rt] = __expf(lv * inv);
            den += e[rt];
          }
#pragma unroll
          for (int m = 1; m < 16; m <<= 1) den += __shfl_xor(den, m, 64);
          const float sc = (lg < len) ? 4.f / den : 0.f;  // SMOOTH, masked
#pragma unroll
          for (int rt = 0; rt < 16; ++rt) {
            const float v = acc[tl][rt][reg] * 0.04419417382415922f;
            const float a = e[rt] * sc;
            w12p[rt] += a * v;  // raw S -> cosine numerator
            if (reg & 1)
              pk[rt][reg >> 1] = pkbf(a0s[rt], a);
            else
              a0s[rt] = a;
          }
        }
        const int lg0 = w * 32 + tl * 16 + quad * 4;
#pragma unroll
        for (int rt = 0; rt < 16; ++rt)
          *(uint2*)(sAt + satIdx(rt * 16 + l16, lg0)) = *(uint2*)pk[rt];
      }
    } else {
      // Zero this wave's sAt columns so nsq's full-width reads see exact
      // zeros (attn == 0 beyond len).
      uint2 z;
      z.x = 0u;
      z.y = 0u;
#pragma unroll
      for (int tl = 0; tl < 2; ++tl) {
        const int lg0 = w * 32 + tl * 16 + quad * 4;
#pragma unroll
        for (int rt = 0; rt < 16; ++rt)
          *(uint2*)(sAt + satIdx(rt * 16 + l16, lg0)) = z;
      }
    }
  }

  // Reduce w12 partials across quads; keep in registers through phase B.
  // (Inactive waves contribute zeros.)
#pragma unroll
  for (int rt = 0; rt < 16; ++rt) {
    w12p[rt] += __shfl_xor(w12p[rt], 16, 64);
    w12p[rt] += __shfl_xor(w12p[rt], 32, 64);
  }

  // ---------------- Phase B (k capped at nCh = ceil(len/32)) ----------------
  float nsv[2][4];
  {
    v4f acc[2][16];
#pragma unroll
    for (int a = 0; a < 2; ++a)
#pragma unroll
      for (int b = 0; b < 16; ++b) acc[a][b] = (v4f){0.f, 0.f, 0.f, 0.f};

    __syncthreads();  // sAt writes complete; G chunks 0,1 staged (drained)

    for (int ch = 0; ch < nCh; ++ch) {
      const int lk = ch << 5;
      if (ch) __syncthreads();  // drains chunk-ch staging; frees buf[(ch+1)&1]
      v8s af0 = *(const v8s*)(sAt + satIdx(w * 32 + l16, lk + quad * 8));
      v8s af1 = *(const v8s*)(sAt + satIdx(w * 32 + 16 + l16, lk + quad * 8));
      __builtin_amdgcn_sched_barrier(0);
      if (ch > 0 && ch < nCh - 1) {  // prefetch chunk ch+1 (ch0/ch1 hoisted)
        char* dst = stage + ((ch + 1) & 1) * 16384;
#pragma unroll
        for (int i = 0; i < 2; ++i)
          gl2lds16(Gn + (i * 128 + rQ) * LN + (lk + 32) + subx * 8,
                   dst + i * 8192 + t * 16);
      }
      __builtin_amdgcn_sched_barrier(0);
      const unsigned short* gs =
          (const unsigned short*)(stage + (ch & 1) * 16384);
      __builtin_amdgcn_s_setprio(1);
#pragma unroll
      for (int lt = 0; lt < 16; ++lt) {
        v8s bf = *stgFrag(gs, lt * 16 + l16, quad);  // G row (symmetric)
        acc[0][lt] = __builtin_amdgcn_mfma_f32_16x16x32_bf16(af0, bf, acc[0][lt], 0, 0, 0);
        acc[1][lt] = __builtin_amdgcn_mfma_f32_16x16x32_bf16(af1, bf, acc[1][lt], 0, 0, 0);
      }
      __builtin_amdgcn_s_setprio(0);
    }
    // nsq[r] = sum_l At[r,l] * U[r,l]; tiles with lt*16 >= len are exact
    // zeros in sAt -> skip (wave-uniform branch, static lt/acc indexing).
#pragma unroll
    for (int tl = 0; tl < 2; ++tl) {
#pragma unroll
      for (int reg = 0; reg < 4; ++reg) {
        const int r = w * 32 + tl * 16 + quad * 4 + reg;
        float s = 0.f;
#pragma unroll
        for (int lt = 0; lt < 16; ++lt) {
          if ((lt << 4) < len)
            s += acc[tl][lt][reg] * bf2f(sAt[satIdx(r, lt * 16 + l16)]);
        }
#pragma unroll
        for (int m = 1; m < 16; m <<= 1) s += __shfl_xor(s, m, 64);
        nsv[tl][reg] = s;
      }
    }
  }

  // ---------------- Phase C (reductions overlay the stage region) ----------
  float* w12s = (float*)stage;           // [8][256] = 8K
  float* nsqS = (float*)(stage + 8192);  // [256]    = 1K
  float* red = (float*)(stage + 9216);   // [8]
  __syncthreads();  // all Gs reads done; stage is free for reductions
  if (l16 == 0) {
#pragma unroll
    for (int tl = 0; tl < 2; ++tl)
#pragma unroll
      for (int reg = 0; reg < 4; ++reg)
        nsqS[w * 32 + tl * 16 + quad * 4 + reg] = nsv[tl][reg];
  }
  if (lane < 16) {
#pragma unroll
    for (int rt = 0; rt < 16; ++rt) w12s[w * 256 + rt * 16 + lane] = w12p[rt];
  }
  __syncthreads();
  float p = 0.f;
  if (t < 256) {
    float w12 = 0.f;
#pragma unroll
    for (int i = 0; i < 8; ++i) w12 += w12s[i * 256 + t];
    const float w1 = cnorm[c * RN + t];
    const float w2 = sqrtf(fmaxf(nsqS[t], 0.f));
    const float sim = (w12 * 22.627416997969522f) / fmaxf(w1 * w2, 1e-8f);
    p = __expf(6.f * sim);
  }
#pragma unroll
  for (int m = 1; m < 64; m <<= 1) p += __shfl_xor(p, m, 64);
  if (lane == 0) red[w] = p;
  __syncthreads();
  if (t == 0) {
    float s = 0.f;
#pragma unroll
    for (int i = 0; i < 8; ++i) s += red[i];
    out[c * NN + n] = logf(s) / 6.f;
  }
}

// ---------------------------------------------------------------------------
extern "C" void kernel_launch(void* const* d_in, const int* in_sizes, int n_in,
                              void* d_out, int out_size, void* d_ws, size_t ws_size,
                              hipStream_t stream) {
  (void)in_sizes; (void)n_in; (void)out_size;
  const float* contracts = (const float*)d_in[0];
  const float* laws = (const float*)d_in[1];
  const int* law_lens = (const int*)d_in[2];
  float* out = (float*)d_out;

  // Workspace layout (21,004,288 B total)
  unsigned short* lawsB = (unsigned short*)d_ws;  // 8 MiB
  unsigned short* conB = lawsB + NN * LN * DN;    // 8 MiB
  unsigned short* G = conB + CN * RN * DN;        // 4 MiB
  float* cnorm = (float*)(G + NN * LN * LN);      // 32 KiB
  if (ws_size < (size_t)21004288) return;

  hipFuncSetAttribute((const void*)setup_kernel,
                      hipFuncAttributeMaxDynamicSharedMemorySize, 131072);
  hipFuncSetAttribute((const void*)main_kernel,
                      hipFuncAttributeMaxDynamicSharedMemorySize, SMEM_TOTAL);

  // 256 blocks: gram stripe + 1/256th of the bf16 conversions each.
  setup_kernel<<<256, 512, 131072, stream>>>(contracts, laws, lawsB, conB,
                                             cnorm, G);
  main_kernel<<<1024, 512, SMEM_TOTAL, stream>>>(law_lens, lawsB, conB, G,
                                                 cnorm, out);
}

// Round 10
// 232.876 us; speedup vs baseline: 1.1363x; 1.0312x over previous
//
#include <hip/hip_runtime.h>
#include <hip/hip_bf16.h>

// Sizes fixed by the reference problem.
#define CN 32
#define RN 256
#define DN 512
#define NN 32
#define LN 256

// LDS layout of main kernel (bytes):
//  sAt   : bf16 [256][256] = 131072, 16B-chunk XOR swizzle (chunk ^= r&7)
//  stage : 32768 = double-buffered staging (conS / Gs), 16K per buffer.
//          Epilogue reductions (w12s 8K, nsqS 1K, red) overlay this region.
//  total : 163840 = 160 KiB.
// Design-space map (measured): 512 threads / 8 waves / 2 per SIMD is the
// ONLY shape where acc (128 AGPR) + working set fit the 256-reg/wave budget
// (R15: M=64 spills; R16: 16-wave 128-reg cap spills; R19: counted-vmcnt
// needs cross-barrier af regs -> spills). Runtime guards inside unrolled hot
// loops break the pipeline (R14 MFMA-loop, R20 nsq-loop: both ~12-20us
// regressions). R18 (__syncthreads + af reg dbuf + setprio + G dbl-hoist)
// is the measured optimum of this structure: 147.2us main.
#define STAGE_OFF 131072
#define SMEM_TOTAL 163840

typedef short v8s __attribute__((ext_vector_type(8)));
typedef float v4f __attribute__((ext_vector_type(4)));
typedef const __attribute__((address_space(1))) void* gas1_t;
typedef __attribute__((address_space(3))) void* las3_t;

__device__ __forceinline__ void gl2lds16(const void* g, void* l) {
  __builtin_amdgcn_global_load_lds((gas1_t)g, (las3_t)l, 16, 0, 0);
}

__device__ __forceinline__ unsigned short f2bf(float x) {
  unsigned int u = __float_as_uint(x);
  u = (u + 0x7fffu + ((u >> 16) & 1u)) >> 16;  // RNE
  return (unsigned short)u;
}
__device__ __forceinline__ float bf2f(unsigned short h) {
  return __uint_as_float(((unsigned int)h) << 16);
}

// Packed RNE f32x2 -> bf16x2 (v_cvt_pk_bf16_f32 on gfx950); a -> low 16.
__device__ __forceinline__ unsigned int pkbf(float a, float b) {
  __hip_bfloat162 h = __float22bfloat162_rn(make_float2(a, b));
  unsigned int u;
  __builtin_memcpy(&u, &h, sizeof(u));
  return u;
}

// Staging buffers ([256][32] shorts): 16B chunks XOR-swizzled with (r>>1)&3.
// Writes absorb the swizzle in the global fetch column; reads via this helper.
__device__ __forceinline__ const v8s* stgFrag(const unsigned short* buf, int r,
                                              int quad) {
  return (const v8s*)(buf + r * 32 + ((quad ^ ((r >> 1) & 3)) << 3));
}

// sAt addressing: row-major stride 256 shorts, 16B chunks XOR-swizzled by row.
__device__ __forceinline__ int satIdx(int r, int col) {
  return (r << 8) | ((((col >> 3) ^ (r & 7)) << 3) | (col & 7));
}

// Read an 8-float fragment from the fp32 gram slice [256][64] (32B chunks
// rotated by row) and convert to bf16x8.
__device__ __forceinline__ v8s ldFrag64(const float* buf, int r, int cp) {
  const float* p = buf + r * 64 + (((cp + r) & 7) << 3);
  const float4 x0 = ((const float4*)p)[0];
  const float4 x1 = ((const float4*)p)[1];
  unsigned short h[8];
  h[0] = f2bf(x0.x); h[1] = f2bf(x0.y); h[2] = f2bf(x0.z); h[3] = f2bf(x0.w);
  h[4] = f2bf(x1.x); h[5] = f2bf(x1.y); h[6] = f2bf(x1.z); h[7] = f2bf(x1.w);
  return *(v8s*)h;
}

// ---------------------------------------------------------------------------
// Fused setup: 256 blocks x 512 threads (1 block/CU). Each block: gram
// chunk-0 staging issued first, 1/256th of the bf16 conversions (hides the
// staging latency), then the double-buffered gram K-loop
// (G[n] = laws[n]@laws[n]^T, 32-row output stripe per block).
// ---------------------------------------------------------------------------
__global__ __launch_bounds__(512) void setup_kernel(
    const float* __restrict__ con, const float* __restrict__ laws,
    unsigned short* __restrict__ lawsB, unsigned short* __restrict__ conB,
    float* __restrict__ cnorm, unsigned short* __restrict__ G) {
  extern __shared__ float slice[];  // 2 x [256*64] fp32, row-rotated 32B chunks
  const int bid = blockIdx.x;       // 256 blocks
  const int t = threadIdx.x;
  const int n = bid >> 3;
  const int m0 = (bid & 7) << 5;  // 32-row output stripe of G[n]
  const int lane = t & 63;
  const int w = t >> 6;
  const int quad = lane >> 4;
  const int l16 = lane & 15;
  const int rg = w >> 2;  // 0..1
  const int cg = w & 3;   // 0..3
  const float* lawN = laws + n * (LN * DN);

  // (1) Issue gram chunk-0 staging into buf0 (in flight during conversions).
#pragma unroll
  for (int i = 0; i < 8; ++i) {
    const int s = i * 512 + t;
    const int row = s >> 4;
    const int p = s & 15;
    const int srcCol = ((((p >> 1) - row) & 7) << 3) + ((p & 1) << 2);
    gl2lds16(lawN + row * DN + srcCol, (char*)slice + s * 16);
  }

  // (2a) laws fp32 -> bf16: this block's 16384-float slice.
#pragma unroll
  for (int p = 0; p < 4; ++p) {
    const int off = bid * 16384 + p * 4096 + t * 8;
    const float4* src = (const float4*)(laws + off);
    float4 x0 = src[0], x1 = src[1];
    unsigned short h[8];
    h[0] = f2bf(x0.x); h[1] = f2bf(x0.y); h[2] = f2bf(x0.z); h[3] = f2bf(x0.w);
    h[4] = f2bf(x1.x); h[5] = f2bf(x1.y); h[6] = f2bf(x1.z); h[7] = f2bf(x1.w);
    *(v8s*)(lawsB + off) = *(v8s*)h;
  }
  // (2b) contracts fp32 -> bf16 + row norms: 32 rows (one wave-row per pass).
#pragma unroll
  for (int p = 0; p < 4; ++p) {
    const int r = bid * 32 + p * 8 + w;
    const float4* src = (const float4*)(con + r * DN + lane * 8);
    float4 x0 = src[0], x1 = src[1];
    unsigned short h[8];
    h[0] = f2bf(x0.x); h[1] = f2bf(x0.y); h[2] = f2bf(x0.z); h[3] = f2bf(x0.w);
    h[4] = f2bf(x1.x); h[5] = f2bf(x1.y); h[6] = f2bf(x1.z); h[7] = f2bf(x1.w);
    *(v8s*)(conB + r * DN + lane * 8) = *(v8s*)h;
    float s = x0.x * x0.x + x0.y * x0.y + x0.z * x0.z + x0.w * x0.w +
              x1.x * x1.x + x1.y * x1.y + x1.z * x1.z + x1.w * x1.w;
#pragma unroll
    for (int m = 1; m < 64; m <<= 1) s += __shfl_xor(s, m, 64);
    if (lane == 0) cnorm[r] = sqrtf(s);
  }

  // (3) Gram K-loop, double-buffered.
  v4f acc[4];
#pragma unroll
  for (int b = 0; b < 4; ++b) acc[b] = (v4f){0.f, 0.f, 0.f, 0.f};

  for (int ch = 0; ch < 8; ++ch) {
    __syncthreads();  // buf[ch&1] staged (chunk-ch load has been in flight)
    if (ch < 7) {     // prefetch chunk ch+1 into the other buffer
      const int dk = (ch + 1) << 6;
      char* dst = (char*)slice + ((ch + 1) & 1) * 65536;
#pragma unroll
      for (int i = 0; i < 8; ++i) {
        const int s = i * 512 + t;
        const int row = s >> 4;
        const int p = s & 15;
        const int srcCol = ((((p >> 1) - row) & 7) << 3) + ((p & 1) << 2);
        gl2lds16(lawN + row * DN + dk + srcCol, dst + s * 16);
      }
    }
    const float* buf = slice + (ch & 1) * 16384;
#pragma unroll
    for (int step = 0; step < 2; ++step) {
      const int cp = quad + (step << 2);
      v8s af = ldFrag64(buf, m0 + rg * 16 + l16, cp);
#pragma unroll
      for (int ct = 0; ct < 4; ++ct) {
        v8s bf = ldFrag64(buf, cg * 64 + ct * 16 + l16, cp);
        acc[ct] = __builtin_amdgcn_mfma_f32_16x16x32_bf16(af, bf, acc[ct], 0, 0, 0);
      }
    }
  }
  unsigned short* g = G + n * (LN * LN);
#pragma unroll
  for (int ct = 0; ct < 4; ++ct)
#pragma unroll
    for (int reg = 0; reg < 4; ++reg) {
      const int l = m0 + rg * 16 + quad * 4 + reg;
      g[l * LN + cg * 64 + ct * 16 + l16] = f2bf(acc[ct][reg]);
    }
}

// ---------------------------------------------------------------------------
// Main: one block per (n,c), 512 threads (8 waves). EXACT R18 structure
// (measured best: 147.2us main) + R21: XCD-clustered (n,c) decode.
// Old: n=bid>>5 -> consecutive blocks (same n) round-robin over 8 XCDs, so
// every XCD touches all 32 lawN (8MB) + all 32 Gn (4MB) + all conC (8MB) --
// 20MB vs 4MB L2 -> staging/A-frag loads miss L2 (FETCH 52MB vs 20MB data).
// New (bijective): n=(bid&7)*4+(bid>>8), c=(bid>>3)&31. With round-robin
// XCD dispatch (bid%8), each XCD serves n in {4x..4x+3}: its lawN (1MB) and
// Gn (512KB) become L2-resident -- exactly the latency-critical per-chunk
// A-frag loads and phase-B G staging. conC still streams (prefetched 1
// chunk ahead).
// ---------------------------------------------------------------------------
__global__ __launch_bounds__(512, 2) void main_kernel(
    const int* __restrict__ law_lens, const unsigned short* __restrict__ lawsB,
    const unsigned short* __restrict__ conB, const unsigned short* __restrict__ Gm,
    const float* __restrict__ cnorm, float* __restrict__ out) {
  extern __shared__ char smem[];
  unsigned short* sAt = (unsigned short*)smem;  // [256][256] swizzled
  char* stage = smem + STAGE_OFF;               // 2 x 16K buffers

  const int bid = blockIdx.x;
  const int n = (bid & 7) * 4 + (bid >> 8);  // XCD-clustered decode
  const int c = (bid >> 3) & 31;
  const int t = threadIdx.x;
  const int lane = t & 63;
  const int w = t >> 6;  // wave 0..7
  const int quad = lane >> 4;
  const int l16 = lane & 15;
  const int sub = t & 3;
  const int rQ = t >> 2;                   // 0..127
  const int subx = sub ^ ((rQ >> 1) & 3);  // swizzled source chunk
  const int len = law_lens[n];
  const int nCh = (len + 31) >> 5;         // phase-B k-chunks (block-uniform)
  const bool active = (w * 32) < len;      // wave has live l-rows in phase A

  const unsigned short* lawN = lawsB + n * (LN * DN);
  const unsigned short* conC = conB + c * (RN * DN);
  const unsigned short* Gn = Gm + n * (LN * LN);

  float w12p[16];
#pragma unroll
  for (int i = 0; i < 16; ++i) w12p[i] = 0.f;

  // ---------------- Phase A ----------------
  {
    const unsigned short* a0p = lawN + (w * 32 + l16) * DN + quad * 8;
    const unsigned short* a1p = a0p + 16 * DN;

    v4f acc[2][16];
#pragma unroll
    for (int a = 0; a < 2; ++a)
#pragma unroll
      for (int b = 0; b < 16; ++b) acc[a][b] = (v4f){0.f, 0.f, 0.f, 0.f};

    // Prologue: stage con chunk 0 into buf0 + load af(chunk 0) into afA.
#pragma unroll
    for (int i = 0; i < 2; ++i)
      gl2lds16(conC + (i * 128 + rQ) * DN + subx * 8,
               stage + i * 8192 + t * 16);
    v8s afA0 = *(const v8s*)(a0p);
    v8s afA1 = *(const v8s*)(a1p);

#pragma unroll
    for (int ch = 0; ch < 16; ch += 2) {
      // ---- even chunk ch: compute from buf0 with afA; prefetch ch+1 ----
      __syncthreads();  // drains chunk-ch staging + afA loads (all overlapped)
      v8s afB0, afB1;
      {
        const int dkn = (ch + 1) << 5;  // ch+1 <= 15 always here
#pragma unroll
        for (int i = 0; i < 2; ++i)
          gl2lds16(conC + (i * 128 + rQ) * DN + dkn + subx * 8,
                   stage + 16384 + i * 8192 + t * 16);
        afB0 = *(const v8s*)(a0p + dkn);
        afB1 = *(const v8s*)(a1p + dkn);
      }
      __builtin_amdgcn_sched_barrier(0);
      if (active) {  // wave-uniform: inactive waves produce only zeros below
        const unsigned short* cs = (const unsigned short*)stage;
        __builtin_amdgcn_s_setprio(1);
#pragma unroll
        for (int rt = 0; rt < 16; ++rt) {
          v8s bf = *stgFrag(cs, rt * 16 + l16, quad);
          acc[0][rt] = __builtin_amdgcn_mfma_f32_16x16x32_bf16(afA0, bf, acc[0][rt], 0, 0, 0);
          acc[1][rt] = __builtin_amdgcn_mfma_f32_16x16x32_bf16(afA1, bf, acc[1][rt], 0, 0, 0);
        }
        __builtin_amdgcn_s_setprio(0);
      }
      // ---- odd chunk ch+1: compute from buf1 with afB; prefetch ch+2 ----
      __syncthreads();  // drains chunk-(ch+1) staging + afB loads
      if (ch + 2 < 16) {
        const int dkn = (ch + 2) << 5;
#pragma unroll
        for (int i = 0; i < 2; ++i)
          gl2lds16(conC + (i * 128 + rQ) * DN + dkn + subx * 8,
                   stage + i * 8192 + t * 16);
        afA0 = *(const v8s*)(a0p + dkn);
        afA1 = *(const v8s*)(a1p + dkn);
      }
      __builtin_amdgcn_sched_barrier(0);
      if (active) {
        const unsigned short* cs = (const unsigned short*)(stage + 16384);
        __builtin_amdgcn_s_setprio(1);
#pragma unroll
        for (int rt = 0; rt < 16; ++rt) {
          v8s bf = *stgFrag(cs, rt * 16 + l16, quad);
          acc[0][rt] = __builtin_amdgcn_mfma_f32_16x16x32_bf16(afB0, bf, acc[0][rt], 0, 0, 0);
          acc[1][rt] = __builtin_amdgcn_mfma_f32_16x16x32_bf16(afB1, bf, acc[1][rt], 0, 0, 0);
        }
        __builtin_amdgcn_s_setprio(0);
      }
    }

    __syncthreads();  // all staging reads done; both stage buffers reusable

    // Hoisted: stage G chunks 0 AND 1 NOW (buf0 and buf1) -- latency hides
    // under the softmax VALU below; phase B's first barrier drains both.
#pragma unroll
    for (int i = 0; i < 2; ++i)
      gl2lds16(Gn + (i * 128 + rQ) * LN + subx * 8, stage + i * 8192 + t * 16);
#pragma unroll
    for (int i = 0; i < 2; ++i)
      gl2lds16(Gn + (i * 128 + rQ) * LN + 32 + subx * 8,
               stage + 16384 + i * 8192 + t * 16);

    if (active) {
      // Softmax row ops (streaming; |lv*inv| <= 1 so exp needs no max-sub).
      // Row l lives in 16 lanes (C layout col=lane&15 -> r index). 4 regs =
      // 4 consecutive sAt columns -> packed cvt + b64 writes.
#pragma unroll
      for (int tl = 0; tl < 2; ++tl) {
        unsigned int pk[16][2];
        float a0s[16];
#pragma unroll
        for (int reg = 0; reg < 4; ++reg) {
          const int lg = w * 32 + tl * 16 + quad * 4 + reg;
          float ss = 0.f;
#pragma unroll
          for (int rt = 0; rt < 16; ++rt) {
            const float v = acc[tl][rt][reg] * 0.04419417382415922f;
            const float lv = v > 0.f ? v : 0.1f * v;
            ss += lv * lv;
          }
#pragma unroll
          for (int m = 1; m < 16; m <<= 1) ss += __shfl_xor(ss, m, 64);
          const float inv = 1.f / (sqrtf(ss) + 1e-8f);
          float e[16];
          float den = 0.f;
#pragma unroll
          for (int rt = 0; rt < 16; ++rt) {
            const float v = acc[tl][rt][reg] * 0.04419417382415922f;
            const float lv = v > 0.f ? v : 0.1f * v;
            e[rt] = __expf(lv * inv);
            den += e[rt];
          }
#pragma unroll
          for (int m = 1; m < 16; m <<= 1) den += __shfl_xor(den, m, 64);
          const float sc = (lg < len) ? 4.f / den : 0.f;  // SMOOTH, masked
#pragma unroll
          for (int rt = 0; rt < 16; ++rt) {
            const float v = acc[tl][rt][reg] * 0.04419417382415922f;
            const float a = e[rt] * sc;
            w12p[rt] += a * v;  // raw S -> cosine numerator
            if (reg & 1)
              pk[rt][reg >> 1] = pkbf(a0s[rt], a);
            else
              a0s[rt] = a;
          }
        }
        const int lg0 = w * 32 + tl * 16 + quad * 4;
#pragma unroll
        for (int rt = 0; rt < 16; ++rt)
          *(uint2*)(sAt + satIdx(rt * 16 + l16, lg0)) = *(uint2*)pk[rt];
      }
    } else {
      // Zero this wave's sAt columns so nsq's full-width reads see exact
      // zeros (attn == 0 beyond len).
      uint2 z;
      z.x = 0u;
      z.y = 0u;
#pragma unroll
      for (int tl = 0; tl < 2; ++tl) {
        const int lg0 = w * 32 + tl * 16 + quad * 4;
#pragma unroll
        for (int rt = 0; rt < 16; ++rt)
          *(uint2*)(sAt + satIdx(rt * 16 + l16, lg0)) = z;
      }
    }
  }

  // Reduce w12 partials across quads; keep in registers through phase B.
  // (Inactive waves contribute zeros.)
#pragma unroll
  for (int rt = 0; rt < 16; ++rt) {
    w12p[rt] += __shfl_xor(w12p[rt], 16, 64);
    w12p[rt] += __shfl_xor(w12p[rt], 32, 64);
  }

  // ---------------- Phase B (k capped at nCh = ceil(len/32)) ----------------
  float nsv[2][4];
  {
    v4f acc[2][16];
#pragma unroll
    for (int a = 0; a < 2; ++a)
#pragma unroll
      for (int b = 0; b < 16; ++b) acc[a][b] = (v4f){0.f, 0.f, 0.f, 0.f};

    __syncthreads();  // sAt writes complete; G chunks 0,1 staged (drained)

    for (int ch = 0; ch < nCh; ++ch) {
      const int lk = ch << 5;
      if (ch) __syncthreads();  // drains chunk-ch staging; frees buf[(ch+1)&1]
      v8s af0 = *(const v8s*)(sAt + satIdx(w * 32 + l16, lk + quad * 8));
      v8s af1 = *(const v8s*)(sAt + satIdx(w * 32 + 16 + l16, lk + quad * 8));
      __builtin_amdgcn_sched_barrier(0);
      if (ch > 0 && ch < nCh - 1) {  // prefetch chunk ch+1 (ch0/ch1 hoisted)
        char* dst = stage + ((ch + 1) & 1) * 16384;
#pragma unroll
        for (int i = 0; i < 2; ++i)
          gl2lds16(Gn + (i * 128 + rQ) * LN + (lk + 32) + subx * 8,
                   dst + i * 8192 + t * 16);
      }
      __builtin_amdgcn_sched_barrier(0);
      const unsigned short* gs =
          (const unsigned short*)(stage + (ch & 1) * 16384);
      __builtin_amdgcn_s_setprio(1);
#pragma unroll
      for (int lt = 0; lt < 16; ++lt) {
        v8s bf = *stgFrag(gs, lt * 16 + l16, quad);  // G row (symmetric)
        acc[0][lt] = __builtin_amdgcn_mfma_f32_16x16x32_bf16(af0, bf, acc[0][lt], 0, 0, 0);
        acc[1][lt] = __builtin_amdgcn_mfma_f32_16x16x32_bf16(af1, bf, acc[1][lt], 0, 0, 0);
      }
      __builtin_amdgcn_s_setprio(0);
    }
    // nsq[r] = sum_l At[r,l] * U[r,l] (sAt cols >= len are exact zeros)
#pragma unroll
    for (int tl = 0; tl < 2; ++tl) {
#pragma unroll
      for (int reg = 0; reg < 4; ++reg) {
        const int r = w * 32 + tl * 16 + quad * 4 + reg;
        float s = 0.f;
#pragma unroll
        for (int lt = 0; lt < 16; ++lt)
          s += acc[tl][lt][reg] * bf2f(sAt[satIdx(r, lt * 16 + l16)]);
#pragma unroll
        for (int m = 1; m < 16; m <<= 1) s += __shfl_xor(s, m, 64);
        nsv[tl][reg] = s;
      }
    }
  }

  // ---------------- Phase C (reductions overlay the stage region) ----------
  float* w12s = (float*)stage;           // [8][256] = 8K
  float* nsqS = (float*)(stage + 8192);  // [256]    = 1K
  float* red = (float*)(stage + 9216);   // [8]
  __syncthreads();  // all Gs reads done; stage is free for reductions
  if (l16 == 0) {
#pragma unroll
    for (int tl = 0; tl < 2; ++tl)
#pragma unroll
      for (int reg = 0; reg < 4; ++reg)
        nsqS[w * 32 + tl * 16 + quad * 4 + reg] = nsv[tl][reg];
  }
  if (lane < 16) {
#pragma unroll
    for (int rt = 0; rt < 16; ++rt) w12s[w * 256 + rt * 16 + lane] = w12p[rt];
  }
  __syncthreads();
  float p = 0.f;
  if (t < 256) {
    float w12 = 0.f;
#pragma unroll
    for (int i = 0; i < 8; ++i) w12 += w12s[i * 256 + t];
    const float w1 = cnorm[c * RN + t];
    const float w2 = sqrtf(fmaxf(nsqS[t], 0.f));
    const float sim = (w12 * 22.627416997969522f) / fmaxf(w1 * w2, 1e-8f);
    p = __expf(6.f * sim);
  }
#pragma unroll
  for (int m = 1; m < 64; m <<= 1) p += __shfl_xor(p, m, 64);
  if (lane == 0) red[w] = p;
  __syncthreads();
  if (t == 0) {
    float s = 0.f;
#pragma unroll
    for (int i = 0; i < 8; ++i) s += red[i];
    out[c * NN + n] = logf(s) / 6.f;
  }
}

// ---------------------------------------------------------------------------
extern "C" void kernel_launch(void* const* d_in, const int* in_sizes, int n_in,
                              void* d_out, int out_size, void* d_ws, size_t ws_size,
                              hipStream_t stream) {
  (void)in_sizes; (void)n_in; (void)out_size;
  const float* contracts = (const float*)d_in[0];
  const float* laws = (const float*)d_in[1];
  const int* law_lens = (const int*)d_in[2];
  float* out = (float*)d_out;

  // Workspace layout (21,004,288 B total)
  unsigned short* lawsB = (unsigned short*)d_ws;  // 8 MiB
  unsigned short* conB = lawsB + NN * LN * DN;    // 8 MiB
  unsigned short* G = conB + CN * RN * DN;        // 4 MiB
  float* cnorm = (float*)(G + NN * LN * LN);      // 32 KiB
  if (ws_size < (size_t)21004288) return;

  hipFuncSetAttribute((const void*)setup_kernel,
                      hipFuncAttributeMaxDynamicSharedMemorySize, 131072);
  hipFuncSetAttribute((const void*)main_kernel,
                      hipFuncAttributeMaxDynamicSharedMemorySize, SMEM_TOTAL);

  // 256 blocks: gram stripe + 1/256th of the bf16 conversions each.
  setup_kernel<<<256, 512, 131072, stream>>>(contracts, laws, lawsB, conB,
                                             cnorm, G);
  main_kernel<<<1024, 512, SMEM_TOTAL, stream>>>(law_lens, lawsB, conB, G,
                                                 cnorm, out);
}

// Round 11
// 227.186 us; speedup vs baseline: 1.1648x; 1.0250x over previous
//
#include <hip/hip_runtime.h>
#include <hip/hip_bf16.h>

// Sizes fixed by the reference problem.
#define CN 32
#define RN 256
#define DN 512
#define NN 32
#define LN 256

// LDS layout of main kernel (bytes):
//  sAt   : bf16 [256][256] = 131072, 16B-chunk XOR swizzle (chunk ^= r&7)
//  stage : 32768 = double-buffered staging (conS / Gs), 16K per buffer.
//          Epilogue reductions (w12s 8K, nsqS 1K, red) overlay this region.
//  total : 163840 = 160 KiB.
// Design-space map (all measured, R12-R21):
//  - 512 thr / 8 waves / 2 per SIMD is the ONLY shape fitting acc(128 AGPR)
//    + working set in 248/256 regs (R15 M=64 spills; R16 16-wave spills).
//  - Counted-vmcnt pipelining spills (R19: cross-barrier af regs).
//  - Runtime guards in unrolled hot loops break the pipeline (R14, R20).
//  - XCD n-clustering thrashes conC sharing, FETCH 52->138MB (R21): the
//    DOMINANT reuse operand is conC; baseline decode keeps ~5MB/XCD.
//  - setprio + G double-hoist ~neutral (kept). af reg dbuf = +15us (R17).
// R18 = this file = measured optimum: 147.2us main / 225.0us total.
#define STAGE_OFF 131072
#define SMEM_TOTAL 163840

typedef short v8s __attribute__((ext_vector_type(8)));
typedef float v4f __attribute__((ext_vector_type(4)));
typedef const __attribute__((address_space(1))) void* gas1_t;
typedef __attribute__((address_space(3))) void* las3_t;

__device__ __forceinline__ void gl2lds16(const void* g, void* l) {
  __builtin_amdgcn_global_load_lds((gas1_t)g, (las3_t)l, 16, 0, 0);
}

__device__ __forceinline__ unsigned short f2bf(float x) {
  unsigned int u = __float_as_uint(x);
  u = (u + 0x7fffu + ((u >> 16) & 1u)) >> 16;  // RNE
  return (unsigned short)u;
}
__device__ __forceinline__ float bf2f(unsigned short h) {
  return __uint_as_float(((unsigned int)h) << 16);
}

// Packed RNE f32x2 -> bf16x2 (v_cvt_pk_bf16_f32 on gfx950); a -> low 16.
__device__ __forceinline__ unsigned int pkbf(float a, float b) {
  __hip_bfloat162 h = __float22bfloat162_rn(make_float2(a, b));
  unsigned int u;
  __builtin_memcpy(&u, &h, sizeof(u));
  return u;
}

// Staging buffers ([256][32] shorts): 16B chunks XOR-swizzled with (r>>1)&3.
// Writes absorb the swizzle in the global fetch column; reads via this helper.
__device__ __forceinline__ const v8s* stgFrag(const unsigned short* buf, int r,
                                              int quad) {
  return (const v8s*)(buf + r * 32 + ((quad ^ ((r >> 1) & 3)) << 3));
}

// sAt addressing: row-major stride 256 shorts, 16B chunks XOR-swizzled by row.
__device__ __forceinline__ int satIdx(int r, int col) {
  return (r << 8) | ((((col >> 3) ^ (r & 7)) << 3) | (col & 7));
}

// Read an 8-float fragment from the fp32 gram slice [256][64] (32B chunks
// rotated by row) and convert to bf16x8.
__device__ __forceinline__ v8s ldFrag64(const float* buf, int r, int cp) {
  const float* p = buf + r * 64 + (((cp + r) & 7) << 3);
  const float4 x0 = ((const float4*)p)[0];
  const float4 x1 = ((const float4*)p)[1];
  unsigned short h[8];
  h[0] = f2bf(x0.x); h[1] = f2bf(x0.y); h[2] = f2bf(x0.z); h[3] = f2bf(x0.w);
  h[4] = f2bf(x1.x); h[5] = f2bf(x1.y); h[6] = f2bf(x1.z); h[7] = f2bf(x1.w);
  return *(v8s*)h;
}

// ---------------------------------------------------------------------------
// Fused setup: 256 blocks x 512 threads (1 block/CU). Each block: gram
// chunk-0 staging issued first, 1/256th of the bf16 conversions (hides the
// staging latency), then the double-buffered gram K-loop
// (G[n] = laws[n]@laws[n]^T, 32-row output stripe per block).
// ---------------------------------------------------------------------------
__global__ __launch_bounds__(512) void setup_kernel(
    const float* __restrict__ con, const float* __restrict__ laws,
    unsigned short* __restrict__ lawsB, unsigned short* __restrict__ conB,
    float* __restrict__ cnorm, unsigned short* __restrict__ G) {
  extern __shared__ float slice[];  // 2 x [256*64] fp32, row-rotated 32B chunks
  const int bid = blockIdx.x;       // 256 blocks
  const int t = threadIdx.x;
  const int n = bid >> 3;
  const int m0 = (bid & 7) << 5;  // 32-row output stripe of G[n]
  const int lane = t & 63;
  const int w = t >> 6;
  const int quad = lane >> 4;
  const int l16 = lane & 15;
  const int rg = w >> 2;  // 0..1
  const int cg = w & 3;   // 0..3
  const float* lawN = laws + n * (LN * DN);

  // (1) Issue gram chunk-0 staging into buf0 (in flight during conversions).
#pragma unroll
  for (int i = 0; i < 8; ++i) {
    const int s = i * 512 + t;
    const int row = s >> 4;
    const int p = s & 15;
    const int srcCol = ((((p >> 1) - row) & 7) << 3) + ((p & 1) << 2);
    gl2lds16(lawN + row * DN + srcCol, (char*)slice + s * 16);
  }

  // (2a) laws fp32 -> bf16: this block's 16384-float slice.
#pragma unroll
  for (int p = 0; p < 4; ++p) {
    const int off = bid * 16384 + p * 4096 + t * 8;
    const float4* src = (const float4*)(laws + off);
    float4 x0 = src[0], x1 = src[1];
    unsigned short h[8];
    h[0] = f2bf(x0.x); h[1] = f2bf(x0.y); h[2] = f2bf(x0.z); h[3] = f2bf(x0.w);
    h[4] = f2bf(x1.x); h[5] = f2bf(x1.y); h[6] = f2bf(x1.z); h[7] = f2bf(x1.w);
    *(v8s*)(lawsB + off) = *(v8s*)h;
  }
  // (2b) contracts fp32 -> bf16 + row norms: 32 rows (one wave-row per pass).
#pragma unroll
  for (int p = 0; p < 4; ++p) {
    const int r = bid * 32 + p * 8 + w;
    const float4* src = (const float4*)(con + r * DN + lane * 8);
    float4 x0 = src[0], x1 = src[1];
    unsigned short h[8];
    h[0] = f2bf(x0.x); h[1] = f2bf(x0.y); h[2] = f2bf(x0.z); h[3] = f2bf(x0.w);
    h[4] = f2bf(x1.x); h[5] = f2bf(x1.y); h[6] = f2bf(x1.z); h[7] = f2bf(x1.w);
    *(v8s*)(conB + r * DN + lane * 8) = *(v8s*)h;
    float s = x0.x * x0.x + x0.y * x0.y + x0.z * x0.z + x0.w * x0.w +
              x1.x * x1.x + x1.y * x1.y + x1.z * x1.z + x1.w * x1.w;
#pragma unroll
    for (int m = 1; m < 64; m <<= 1) s += __shfl_xor(s, m, 64);
    if (lane == 0) cnorm[r] = sqrtf(s);
  }

  // (3) Gram K-loop, double-buffered.
  v4f acc[4];
#pragma unroll
  for (int b = 0; b < 4; ++b) acc[b] = (v4f){0.f, 0.f, 0.f, 0.f};

  for (int ch = 0; ch < 8; ++ch) {
    __syncthreads();  // buf[ch&1] staged (chunk-ch load has been in flight)
    if (ch < 7) {     // prefetch chunk ch+1 into the other buffer
      const int dk = (ch + 1) << 6;
      char* dst = (char*)slice + ((ch + 1) & 1) * 65536;
#pragma unroll
      for (int i = 0; i < 8; ++i) {
        const int s = i * 512 + t;
        const int row = s >> 4;
        const int p = s & 15;
        const int srcCol = ((((p >> 1) - row) & 7) << 3) + ((p & 1) << 2);
        gl2lds16(lawN + row * DN + dk + srcCol, dst + s * 16);
      }
    }
    const float* buf = slice + (ch & 1) * 16384;
#pragma unroll
    for (int step = 0; step < 2; ++step) {
      const int cp = quad + (step << 2);
      v8s af = ldFrag64(buf, m0 + rg * 16 + l16, cp);
#pragma unroll
      for (int ct = 0; ct < 4; ++ct) {
        v8s bf = ldFrag64(buf, cg * 64 + ct * 16 + l16, cp);
        acc[ct] = __builtin_amdgcn_mfma_f32_16x16x32_bf16(af, bf, acc[ct], 0, 0, 0);
      }
    }
  }
  unsigned short* g = G + n * (LN * LN);
#pragma unroll
  for (int ct = 0; ct < 4; ++ct)
#pragma unroll
    for (int reg = 0; reg < 4; ++reg) {
      const int l = m0 + rg * 16 + quad * 4 + reg;
      g[l * LN + cg * 64 + ct * 16 + l16] = f2bf(acc[ct][reg]);
    }
}

// ---------------------------------------------------------------------------
// Main: one block per (n,c), 512 threads (8 waves). EXACT R18 structure
// (measured best: 147.2us main): af register double-buffer (R17), setprio
// around MFMA bursts + G chunks 0,1 double-hoist (R18), baseline (n,c)
// decode n=bid>>5 (R21 proved XCD n-clustering destroys conC L2 sharing).
// ---------------------------------------------------------------------------
__global__ __launch_bounds__(512, 2) void main_kernel(
    const int* __restrict__ law_lens, const unsigned short* __restrict__ lawsB,
    const unsigned short* __restrict__ conB, const unsigned short* __restrict__ Gm,
    const float* __restrict__ cnorm, float* __restrict__ out) {
  extern __shared__ char smem[];
  unsigned short* sAt = (unsigned short*)smem;  // [256][256] swizzled
  char* stage = smem + STAGE_OFF;               // 2 x 16K buffers

  const int bid = blockIdx.x;
  const int n = bid >> 5;  // 32 consecutive blocks share one n
  const int c = bid & 31;
  const int t = threadIdx.x;
  const int lane = t & 63;
  const int w = t >> 6;  // wave 0..7
  const int quad = lane >> 4;
  const int l16 = lane & 15;
  const int sub = t & 3;
  const int rQ = t >> 2;                   // 0..127
  const int subx = sub ^ ((rQ >> 1) & 3);  // swizzled source chunk
  const int len = law_lens[n];
  const int nCh = (len + 31) >> 5;         // phase-B k-chunks (block-uniform)
  const bool active = (w * 32) < len;      // wave has live l-rows in phase A

  const unsigned short* lawN = lawsB + n * (LN * DN);
  const unsigned short* conC = conB + c * (RN * DN);
  const unsigned short* Gn = Gm + n * (LN * LN);

  float w12p[16];
#pragma unroll
  for (int i = 0; i < 16; ++i) w12p[i] = 0.f;

  // ---------------- Phase A ----------------
  {
    const unsigned short* a0p = lawN + (w * 32 + l16) * DN + quad * 8;
    const unsigned short* a1p = a0p + 16 * DN;

    v4f acc[2][16];
#pragma unroll
    for (int a = 0; a < 2; ++a)
#pragma unroll
      for (int b = 0; b < 16; ++b) acc[a][b] = (v4f){0.f, 0.f, 0.f, 0.f};

    // Prologue: stage con chunk 0 into buf0 + load af(chunk 0) into afA.
#pragma unroll
    for (int i = 0; i < 2; ++i)
      gl2lds16(conC + (i * 128 + rQ) * DN + subx * 8,
               stage + i * 8192 + t * 16);
    v8s afA0 = *(const v8s*)(a0p);
    v8s afA1 = *(const v8s*)(a1p);

#pragma unroll
    for (int ch = 0; ch < 16; ch += 2) {
      // ---- even chunk ch: compute from buf0 with afA; prefetch ch+1 ----
      __syncthreads();  // drains chunk-ch staging + afA loads (all overlapped)
      v8s afB0, afB1;
      {
        const int dkn = (ch + 1) << 5;  // ch+1 <= 15 always here
#pragma unroll
        for (int i = 0; i < 2; ++i)
          gl2lds16(conC + (i * 128 + rQ) * DN + dkn + subx * 8,
                   stage + 16384 + i * 8192 + t * 16);
        afB0 = *(const v8s*)(a0p + dkn);
        afB1 = *(const v8s*)(a1p + dkn);
      }
      __builtin_amdgcn_sched_barrier(0);
      if (active) {  // wave-uniform: inactive waves produce only zeros below
        const unsigned short* cs = (const unsigned short*)stage;
        __builtin_amdgcn_s_setprio(1);
#pragma unroll
        for (int rt = 0; rt < 16; ++rt) {
          v8s bf = *stgFrag(cs, rt * 16 + l16, quad);
          acc[0][rt] = __builtin_amdgcn_mfma_f32_16x16x32_bf16(afA0, bf, acc[0][rt], 0, 0, 0);
          acc[1][rt] = __builtin_amdgcn_mfma_f32_16x16x32_bf16(afA1, bf, acc[1][rt], 0, 0, 0);
        }
        __builtin_amdgcn_s_setprio(0);
      }
      // ---- odd chunk ch+1: compute from buf1 with afB; prefetch ch+2 ----
      __syncthreads();  // drains chunk-(ch+1) staging + afB loads
      if (ch + 2 < 16) {
        const int dkn = (ch + 2) << 5;
#pragma unroll
        for (int i = 0; i < 2; ++i)
          gl2lds16(conC + (i * 128 + rQ) * DN + dkn + subx * 8,
                   stage + i * 8192 + t * 16);
        afA0 = *(const v8s*)(a0p + dkn);
        afA1 = *(const v8s*)(a1p + dkn);
      }
      __builtin_amdgcn_sched_barrier(0);
      if (active) {
        const unsigned short* cs = (const unsigned short*)(stage + 16384);
        __builtin_amdgcn_s_setprio(1);
#pragma unroll
        for (int rt = 0; rt < 16; ++rt) {
          v8s bf = *stgFrag(cs, rt * 16 + l16, quad);
          acc[0][rt] = __builtin_amdgcn_mfma_f32_16x16x32_bf16(afB0, bf, acc[0][rt], 0, 0, 0);
          acc[1][rt] = __builtin_amdgcn_mfma_f32_16x16x32_bf16(afB1, bf, acc[1][rt], 0, 0, 0);
        }
        __builtin_amdgcn_s_setprio(0);
      }
    }

    __syncthreads();  // all staging reads done; both stage buffers reusable

    // Hoisted: stage G chunks 0 AND 1 NOW (buf0 and buf1) -- latency hides
    // under the softmax VALU below; phase B's first barrier drains both.
#pragma unroll
    for (int i = 0; i < 2; ++i)
      gl2lds16(Gn + (i * 128 + rQ) * LN + subx * 8, stage + i * 8192 + t * 16);
#pragma unroll
    for (int i = 0; i < 2; ++i)
      gl2lds16(Gn + (i * 128 + rQ) * LN + 32 + subx * 8,
               stage + 16384 + i * 8192 + t * 16);

    if (active) {
      // Softmax row ops (streaming; |lv*inv| <= 1 so exp needs no max-sub).
      // Row l lives in 16 lanes (C layout col=lane&15 -> r index). 4 regs =
      // 4 consecutive sAt columns -> packed cvt + b64 writes.
#pragma unroll
      for (int tl = 0; tl < 2; ++tl) {
        unsigned int pk[16][2];
        float a0s[16];
#pragma unroll
        for (int reg = 0; reg < 4; ++reg) {
          const int lg = w * 32 + tl * 16 + quad * 4 + reg;
          float ss = 0.f;
#pragma unroll
          for (int rt = 0; rt < 16; ++rt) {
            const float v = acc[tl][rt][reg] * 0.04419417382415922f;
            const float lv = v > 0.f ? v : 0.1f * v;
            ss += lv * lv;
          }
#pragma unroll
          for (int m = 1; m < 16; m <<= 1) ss += __shfl_xor(ss, m, 64);
          const float inv = 1.f / (sqrtf(ss) + 1e-8f);
          float e[16];
          float den = 0.f;
#pragma unroll
          for (int rt = 0; rt < 16; ++rt) {
            const float v = acc[tl][rt][reg] * 0.04419417382415922f;
            const float lv = v > 0.f ? v : 0.1f * v;
            e[rt] = __expf(lv * inv);
            den += e[rt];
          }
#pragma unroll
          for (int m = 1; m < 16; m <<= 1) den += __shfl_xor(den, m, 64);
          const float sc = (lg < len) ? 4.f / den : 0.f;  // SMOOTH, masked
#pragma unroll
          for (int rt = 0; rt < 16; ++rt) {
            const float v = acc[tl][rt][reg] * 0.04419417382415922f;
            const float a = e[rt] * sc;
            w12p[rt] += a * v;  // raw S -> cosine numerator
            if (reg & 1)
              pk[rt][reg >> 1] = pkbf(a0s[rt], a);
            else
              a0s[rt] = a;
          }
        }
        const int lg0 = w * 32 + tl * 16 + quad * 4;
#pragma unroll
        for (int rt = 0; rt < 16; ++rt)
          *(uint2*)(sAt + satIdx(rt * 16 + l16, lg0)) = *(uint2*)pk[rt];
      }
    } else {
      // Zero this wave's sAt columns so nsq's full-width reads see exact
      // zeros (attn == 0 beyond len).
      uint2 z;
      z.x = 0u;
      z.y = 0u;
#pragma unroll
      for (int tl = 0; tl < 2; ++tl) {
        const int lg0 = w * 32 + tl * 16 + quad * 4;
#pragma unroll
        for (int rt = 0; rt < 16; ++rt)
          *(uint2*)(sAt + satIdx(rt * 16 + l16, lg0)) = z;
      }
    }
  }

  // Reduce w12 partials across quads; keep in registers through phase B.
  // (Inactive waves contribute zeros.)
#pragma unroll
  for (int rt = 0; rt < 16; ++rt) {
    w12p[rt] += __shfl_xor(w12p[rt], 16, 64);
    w12p[rt] += __shfl_xor(w12p[rt], 32, 64);
  }

  // ---------------- Phase B (k capped at nCh = ceil(len/32)) ----------------
  float nsv[2][4];
  {
    v4f acc[2][16];
#pragma unroll
    for (int a = 0; a < 2; ++a)
#pragma unroll
      for (int b = 0; b < 16; ++b) acc[a][b] = (v4f){0.f, 0.f, 0.f, 0.f};

    __syncthreads();  // sAt writes complete; G chunks 0,1 staged (drained)

    for (int ch = 0; ch < nCh; ++ch) {
      const int lk = ch << 5;
      if (ch) __syncthreads();  // drains chunk-ch staging; frees buf[(ch+1)&1]
      v8s af0 = *(const v8s*)(sAt + satIdx(w * 32 + l16, lk + quad * 8));
      v8s af1 = *(const v8s*)(sAt + satIdx(w * 32 + 16 + l16, lk + quad * 8));
      __builtin_amdgcn_sched_barrier(0);
      if (ch > 0 && ch < nCh - 1) {  // prefetch chunk ch+1 (ch0/ch1 hoisted)
        char* dst = stage + ((ch + 1) & 1) * 16384;
#pragma unroll
        for (int i = 0; i < 2; ++i)
          gl2lds16(Gn + (i * 128 + rQ) * LN + (lk + 32) + subx * 8,
                   dst + i * 8192 + t * 16);
      }
      __builtin_amdgcn_sched_barrier(0);
      const unsigned short* gs =
          (const unsigned short*)(stage + (ch & 1) * 16384);
      __builtin_amdgcn_s_setprio(1);
#pragma unroll
      for (int lt = 0; lt < 16; ++lt) {
        v8s bf = *stgFrag(gs, lt * 16 + l16, quad);  // G row (symmetric)
        acc[0][lt] = __builtin_amdgcn_mfma_f32_16x16x32_bf16(af0, bf, acc[0][lt], 0, 0, 0);
        acc[1][lt] = __builtin_amdgcn_mfma_f32_16x16x32_bf16(af1, bf, acc[1][lt], 0, 0, 0);
      }
      __builtin_amdgcn_s_setprio(0);
    }
    // nsq[r] = sum_l At[r,l] * U[r,l] (sAt cols >= len are exact zeros)
#pragma unroll
    for (int tl = 0; tl < 2; ++tl) {
#pragma unroll
      for (int reg = 0; reg < 4; ++reg) {
        const int r = w * 32 + tl * 16 + quad * 4 + reg;
        float s = 0.f;
#pragma unroll
        for (int lt = 0; lt < 16; ++lt)
          s += acc[tl][lt][reg] * bf2f(sAt[satIdx(r, lt * 16 + l16)]);
#pragma unroll
        for (int m = 1; m < 16; m <<= 1) s += __shfl_xor(s, m, 64);
        nsv[tl][reg] = s;
      }
    }
  }

  // ---------------- Phase C (reductions overlay the stage region) ----------
  float* w12s = (float*)stage;           // [8][256] = 8K
  float* nsqS = (float*)(stage + 8192);  // [256]    = 1K
  float* red = (float*)(stage + 9216);   // [8]
  __syncthreads();  // all Gs reads done; stage is free for reductions
  if (l16 == 0) {
#pragma unroll
    for (int tl = 0; tl < 2; ++tl)
#pragma unroll
      for (int reg = 0; reg < 4; ++reg)
        nsqS[w * 32 + tl * 16 + quad * 4 + reg] = nsv[tl][reg];
  }
  if (lane < 16) {
#pragma unroll
    for (int rt = 0; rt < 16; ++rt) w12s[w * 256 + rt * 16 + lane] = w12p[rt];
  }
  __syncthreads();
  float p = 0.f;
  if (t < 256) {
    float w12 = 0.f;
#pragma unroll
    for (int i = 0; i < 8; ++i) w12 += w12s[i * 256 + t];
    const float w1 = cnorm[c * RN + t];
    const float w2 = sqrtf(fmaxf(nsqS[t], 0.f));
    const float sim = (w12 * 22.627416997969522f) / fmaxf(w1 * w2, 1e-8f);
    p = __expf(6.f * sim);
  }
#pragma unroll
  for (int m = 1; m < 64; m <<= 1) p += __shfl_xor(p, m, 64);
  if (lane == 0) red[w] = p;
  __syncthreads();
  if (t == 0) {
    float s = 0.f;
#pragma unroll
    for (int i = 0; i < 8; ++i) s += red[i];
    out[c * NN + n] = logf(s) / 6.f;
  }
}

// ---------------------------------------------------------------------------
extern "C" void kernel_launch(void* const* d_in, const int* in_sizes, int n_in,
                              void* d_out, int out_size, void* d_ws, size_t ws_size,
                              hipStream_t stream) {
  (void)in_sizes; (void)n_in; (void)out_size;
  const float* contracts = (const float*)d_in[0];
  const float* laws = (const float*)d_in[1];
  const int* law_lens = (const int*)d_in[2];
  float* out = (float*)d_out;

  // Workspace layout (21,004,288 B total)
  unsigned short* lawsB = (unsigned short*)d_ws;  // 8 MiB
  unsigned short* conB = lawsB + NN * LN * DN;    // 8 MiB
  unsigned short* G = conB + CN * RN * DN;        // 4 MiB
  float* cnorm = (float*)(G + NN * LN * LN);      // 32 KiB
  if (ws_size < (size_t)21004288) return;

  hipFuncSetAttribute((const void*)setup_kernel,
                      hipFuncAttributeMaxDynamicSharedMemorySize, 131072);
  hipFuncSetAttribute((const void*)main_kernel,
                      hipFuncAttributeMaxDynamicSharedMemorySize, SMEM_TOTAL);

  // 256 blocks: gram stripe + 1/256th of the bf16 conversions each.
  setup_kernel<<<256, 512, 131072, stream>>>(contracts, laws, lawsB, conB,
                                             cnorm, G);
  main_kernel<<<1024, 512, SMEM_TOTAL, stream>>>(law_lens, lawsB, conB, G,
                                                 cnorm, out);
}